// Round 1
// baseline (951.588 us; speedup 1.0000x reference)
//
#include <hip/hip_runtime.h>

#define B 4
#define N 2048
#define MAXIT 11       // body runs for it = 0..10
#define TOL 1e-4f
#define NT 256
#define CC 512         // candidates per nn block
#define QC 256         // queries per nn block

// ---------------- workspace layout ----------------
// [0,       98304)  float temp_pc[B][N][3]
// [98304,  163840)  unsigned long long nn[B][N]   (packed (d2bits<<32)|idx)
// [163840, 163848)  float prev_err; int done;

// ---------------- 3x3 helpers (double, thread-serial) ----------------
__device__ double det3(const double* M) {
    return M[0]*(M[4]*M[8]-M[5]*M[7])
         - M[1]*(M[3]*M[8]-M[5]*M[6])
         + M[2]*(M[3]*M[7]-M[4]*M[6]);
}

// SVD of 3x3 A (row-major): A = U * diag(sig) * V^T, sig sorted descending.
__device__ void svd3x3(const double* A, double* U, double* V, double* sig) {
    // S = A^T A
    double S[9];
    for (int i = 0; i < 3; ++i)
        for (int j = 0; j < 3; ++j) {
            double s = 0.0;
            for (int k = 0; k < 3; ++k) s += A[k*3+i] * A[k*3+j];
            S[i*3+j] = s;
        }
    double Vm[9] = {1,0,0, 0,1,0, 0,0,1};
    for (int sweep = 0; sweep < 30; ++sweep) {
        double off = fabs(S[1]) + fabs(S[2]) + fabs(S[5]);
        double base = fabs(S[0]) + fabs(S[4]) + fabs(S[8]);
        if (off <= 1e-15 * base) break;
        for (int pi = 0; pi < 3; ++pi) {
            const int p = (pi == 2) ? 1 : 0;
            const int q = (pi == 0) ? 1 : 2;
            double apq = S[p*3+q];
            if (apq == 0.0) continue;
            double app = S[p*3+p], aqq = S[q*3+q];
            double tau = (aqq - app) / (2.0 * apq);
            double tt  = ((tau >= 0.0) ? 1.0 : -1.0) / (fabs(tau) + sqrt(1.0 + tau*tau));
            double c = 1.0 / sqrt(1.0 + tt*tt);
            double s = tt * c;
            for (int k = 0; k < 3; ++k) {          // S = S * J
                double skp = S[k*3+p], skq = S[k*3+q];
                S[k*3+p] = c*skp - s*skq;
                S[k*3+q] = s*skp + c*skq;
            }
            for (int k = 0; k < 3; ++k) {          // S = J^T * S
                double spk = S[p*3+k], sqk = S[q*3+k];
                S[p*3+k] = c*spk - s*sqk;
                S[q*3+k] = s*spk + c*sqk;
            }
            for (int k = 0; k < 3; ++k) {          // V = V * J
                double vkp = Vm[k*3+p], vkq = Vm[k*3+q];
                Vm[k*3+p] = c*vkp - s*vkq;
                Vm[k*3+q] = s*vkp + c*vkq;
            }
        }
    }
    double lam[3] = {S[0], S[4], S[8]};
    int ord[3] = {0, 1, 2};
    for (int i = 0; i < 2; ++i)
        for (int j = i+1; j < 3; ++j)
            if (lam[ord[j]] > lam[ord[i]]) { int tmp = ord[i]; ord[i] = ord[j]; ord[j] = tmp; }
    for (int i = 0; i < 3; ++i) {
        int o = ord[i];
        double l = lam[o] > 0.0 ? lam[o] : 0.0;
        sig[i] = sqrt(l);
        for (int k = 0; k < 3; ++k) V[k*3+i] = Vm[k*3+o];
    }
    // U_i = A * V_i / sigma_i (normalized)
    for (int i = 0; i < 3; ++i) {
        double u0 = 0, u1 = 0, u2 = 0;
        for (int k = 0; k < 3; ++k) {
            u0 += A[0*3+k] * V[k*3+i];
            u1 += A[1*3+k] * V[k*3+i];
            u2 += A[2*3+k] * V[k*3+i];
        }
        double nrm = sqrt(u0*u0 + u1*u1 + u2*u2);
        if (nrm > 1e-300) { u0 /= nrm; u1 /= nrm; u2 /= nrm; }
        else {
            // degenerate: complete with cross of first two columns
            double ax = U[0], ay = U[3], az = U[6];
            double bx = U[1], by = U[4], bz = U[7];
            u0 = ay*bz - az*by; u1 = az*bx - ax*bz; u2 = ax*by - ay*bx;
        }
        U[0*3+i] = u0; U[1*3+i] = u1; U[2*3+i] = u2;
    }
}

// Reference semantics: u,s,vT = svd(H); v=vT^T; d=det(v@u^T); v[2,2]*=d;
// RT = u @ v^T; R = RT^T = v' @ u^T;  t[j] = p2c[j] - sum_k p1c[k]*R[k][j]
__device__ void compute_Rt(const double* H, const double* p1c, const double* p2c,
                           float* Rout, float* tout) {
    double U[9], V[9], sig[3];
    svd3x3(H, U, V, sig);
    double d = (det3(U) * det3(V) < 0.0) ? -1.0 : 1.0;
    V[2*3+2] *= d;
    double R[9];
    for (int i = 0; i < 3; ++i)
        for (int j = 0; j < 3; ++j) {
            double s = 0.0;
            for (int k = 0; k < 3; ++k) s += V[i*3+k] * U[j*3+k];
            R[i*3+j] = s;
        }
    for (int j = 0; j < 3; ++j) {
        double s = 0.0;
        for (int k = 0; k < 3; ++k) s += p1c[k] * R[k*3+j];
        tout[j] = (float)(p2c[j] - s);
    }
    for (int k = 0; k < 9; ++k) Rout[k] = (float)R[k];
}

// ---------------- kernels ----------------
__global__ void __launch_bounds__(256) k_init(const float* __restrict__ p1,
                                              float* __restrict__ temp,
                                              unsigned long long* __restrict__ nn,
                                              float* scal) {
    int i = blockIdx.x * blockDim.x + threadIdx.x;
    if (i < B*N*3) temp[i] = p1[i];
    if (i < B*N)   nn[i] = ~0ULL;
    if (i == 0) { scal[0] = 0.0f; ((int*)scal)[1] = 0; }
}

__global__ void __launch_bounds__(256) k_nn(const float* __restrict__ p2,
                                            const float* __restrict__ temp,
                                            unsigned long long* __restrict__ nn,
                                            const int* __restrict__ done) {
    if (*done) return;
    __shared__ float sc[CC * 3];
    const int b  = blockIdx.z;
    const int qb = blockIdx.y * QC;
    const int cb = blockIdx.x * CC;
    for (int i = threadIdx.x; i < CC*3; i += blockDim.x)
        sc[i] = temp[(b*N + cb)*3 + i];
    __syncthreads();
    const int q = qb + threadIdx.x;
    const float px = p2[(b*N+q)*3+0];
    const float py = p2[(b*N+q)*3+1];
    const float pz = p2[(b*N+q)*3+2];
    float bestd = __uint_as_float(0x7f7fffffu);  // FLT_MAX
    int   besti = 0;
    for (int j = 0; j < CC; ++j) {
        float dx = px - sc[j*3+0];
        float dy = py - sc[j*3+1];
        float dz = pz - sc[j*3+2];
        float d2 = dx*dx + dy*dy + dz*dz;
        if (d2 < bestd) { bestd = d2; besti = cb + j; }
    }
    unsigned long long pack =
        ((unsigned long long)__float_as_uint(bestd) << 32) | (unsigned int)besti;
    atomicMin(&nn[b*N + q], pack);
}

__global__ void __launch_bounds__(256) k_step(const float* __restrict__ p2,
                                              float* __restrict__ temp,
                                              unsigned long long* __restrict__ nn,
                                              float* scal) {
    __shared__ float rbuf[9][NT];
    __shared__ float sR[9], sT[3];
    __shared__ float sc1[3], sc2[3];
    __shared__ float meanerr_s;
    __shared__ int sdone;
    const int t = threadIdx.x;
    int* done = (int*)(scal + 1);
    if (t == 0) sdone = *done;
    __syncthreads();
    if (sdone) return;

    // mean error (vals.mean() over all B*N sqrt distances)
    float s = 0.f;
    for (int i = t; i < B*N; i += NT) {
        unsigned int dbits = (unsigned int)(nn[i] >> 32);
        s += sqrtf(__uint_as_float(dbits));
    }
    rbuf[0][t] = s;
    for (int w = NT/2; w > 0; w >>= 1) {
        __syncthreads();
        if (t < w) rbuf[0][t] += rbuf[0][t + w];
    }
    __syncthreads();
    if (t == 0) meanerr_s = rbuf[0][0] / (float)(B*N);
    __syncthreads();
    const float meanerr = meanerr_s;

    for (int b = 0; b < B; ++b) {
        // phase A: centroids of temp[b] and matched (p2[b] gathered by idx[-1])
        float sx = 0, sy = 0, sz = 0, mx = 0, my = 0, mz = 0;
        for (int i = t; i < N; i += NT) {
            const float* tp = &temp[(b*N + i)*3];
            sx += tp[0]; sy += tp[1]; sz += tp[2];
            const int mi = (int)(unsigned int)(nn[3*N + i] & 0xffffffffULL);
            const float* mp = &p2[(b*N + mi)*3];
            mx += mp[0]; my += mp[1]; mz += mp[2];
        }
        rbuf[0][t] = sx; rbuf[1][t] = sy; rbuf[2][t] = sz;
        rbuf[3][t] = mx; rbuf[4][t] = my; rbuf[5][t] = mz;
        for (int w = NT/2; w > 0; w >>= 1) {
            __syncthreads();
            if (t < w) for (int k = 0; k < 6; ++k) rbuf[k][t] += rbuf[k][t + w];
        }
        __syncthreads();
        if (t == 0) {
            for (int k = 0; k < 3; ++k) {
                sc1[k] = rbuf[k][0]   / (float)N;   // centroid of temp (p1c)
                sc2[k] = rbuf[3+k][0] / (float)N;   // centroid of matched (p2c)
            }
        }
        __syncthreads();
        const float c1x = sc1[0], c1y = sc1[1], c1z = sc1[2];
        const float c2x = sc2[0], c2y = sc2[1], c2z = sc2[2];

        // phase B: H[j][k] = sum_n (matched - p2c)_j * (temp - p1c)_k
        float h[9];
        for (int k = 0; k < 9; ++k) h[k] = 0.f;
        for (int i = t; i < N; i += NT) {
            const float* tp = &temp[(b*N + i)*3];
            const int mi = (int)(unsigned int)(nn[3*N + i] & 0xffffffffULL);
            const float* mp = &p2[(b*N + mi)*3];
            const float bx = tp[0]-c1x, by = tp[1]-c1y, bz = tp[2]-c1z; // q1
            const float ax = mp[0]-c2x, ay = mp[1]-c2y, az = mp[2]-c2z; // q2
            h[0] += ax*bx; h[1] += ax*by; h[2] += ax*bz;
            h[3] += ay*bx; h[4] += ay*by; h[5] += ay*bz;
            h[6] += az*bx; h[7] += az*by; h[8] += az*bz;
        }
        for (int k = 0; k < 9; ++k) rbuf[k][t] = h[k];
        for (int w = NT/2; w > 0; w >>= 1) {
            __syncthreads();
            if (t < w) for (int k = 0; k < 9; ++k) rbuf[k][t] += rbuf[k][t + w];
        }
        __syncthreads();
        if (t == 0) {
            double H[9], c1d[3], c2d[3];
            for (int k = 0; k < 9; ++k) H[k] = (double)rbuf[k][0];
            c1d[0] = c1x; c1d[1] = c1y; c1d[2] = c1z;
            c2d[0] = c2x; c2d[1] = c2y; c2d[2] = c2z;
            compute_Rt(H, c1d, c2d, sR, sT);
        }
        __syncthreads();
        // temp[b] = temp[b] @ R + t
        for (int i = t; i < N; i += NT) {
            float* tp = &temp[(b*N + i)*3];
            const float x = tp[0], y = tp[1], z = tp[2];
            tp[0] = x*sR[0] + y*sR[3] + z*sR[6] + sT[0];
            tp[1] = x*sR[1] + y*sR[4] + z*sR[7] + sT[1];
            tp[2] = x*sR[2] + y*sR[5] + z*sR[8] + sT[2];
        }
        __syncthreads();
    }

    // reset NN slots for next iteration; update prev_err / done
    for (int i = t; i < B*N; i += NT) nn[i] = ~0ULL;
    if (t == 0) {
        const float prev = scal[0];
        scal[0] = meanerr;
        if (fabsf(prev - meanerr) < TOL) *done = 1;
    }
}

__global__ void __launch_bounds__(256) k_final(const float* __restrict__ p1,
                                               const float* __restrict__ temp,
                                               float* __restrict__ out) {
    __shared__ float rbuf[9][NT];
    __shared__ float sR[9], sT[3];
    __shared__ float sc1[3], sc2[3];
    const int t = threadIdx.x;
    for (int b = 0; b < B; ++b) {
        float sx = 0, sy = 0, sz = 0, mx = 0, my = 0, mz = 0;
        for (int i = t; i < N; i += NT) {
            const float* pp = &p1[(b*N + i)*3];
            const float* tp = &temp[(b*N + i)*3];
            sx += pp[0]; sy += pp[1]; sz += pp[2];
            mx += tp[0]; my += tp[1]; mz += tp[2];
        }
        rbuf[0][t] = sx; rbuf[1][t] = sy; rbuf[2][t] = sz;
        rbuf[3][t] = mx; rbuf[4][t] = my; rbuf[5][t] = mz;
        for (int w = NT/2; w > 0; w >>= 1) {
            __syncthreads();
            if (t < w) for (int k = 0; k < 6; ++k) rbuf[k][t] += rbuf[k][t + w];
        }
        __syncthreads();
        if (t == 0) {
            for (int k = 0; k < 3; ++k) {
                sc1[k] = rbuf[k][0]   / (float)N;   // centroid of p1   (p1c)
                sc2[k] = rbuf[3+k][0] / (float)N;   // centroid of temp (p2c)
            }
        }
        __syncthreads();
        const float c1x = sc1[0], c1y = sc1[1], c1z = sc1[2];
        const float c2x = sc2[0], c2y = sc2[1], c2z = sc2[2];

        // H[j][k] = sum_n (temp - c2)_j * (p1 - c1)_k
        float h[9];
        for (int k = 0; k < 9; ++k) h[k] = 0.f;
        for (int i = t; i < N; i += NT) {
            const float* pp = &p1[(b*N + i)*3];
            const float* tp = &temp[(b*N + i)*3];
            const float bx = pp[0]-c1x, by = pp[1]-c1y, bz = pp[2]-c1z; // q1
            const float ax = tp[0]-c2x, ay = tp[1]-c2y, az = tp[2]-c2z; // q2
            h[0] += ax*bx; h[1] += ax*by; h[2] += ax*bz;
            h[3] += ay*bx; h[4] += ay*by; h[5] += ay*bz;
            h[6] += az*bx; h[7] += az*by; h[8] += az*bz;
        }
        for (int k = 0; k < 9; ++k) rbuf[k][t] = h[k];
        for (int w = NT/2; w > 0; w >>= 1) {
            __syncthreads();
            if (t < w) for (int k = 0; k < 9; ++k) rbuf[k][t] += rbuf[k][t + w];
        }
        __syncthreads();
        if (t == 0) {
            double H[9], c1d[3], c2d[3];
            for (int k = 0; k < 9; ++k) H[k] = (double)rbuf[k][0];
            c1d[0] = c1x; c1d[1] = c1y; c1d[2] = c1z;
            c2d[0] = c2x; c2d[1] = c2y; c2d[2] = c2z;
            compute_Rt(H, c1d, c2d, sR, sT);
            // T[b] = [R | t^T]  -> row i: R[i][0..2], t[i]
            for (int i = 0; i < 3; ++i) {
                out[b*12 + i*4 + 0] = sR[i*3+0];
                out[b*12 + i*4 + 1] = sR[i*3+1];
                out[b*12 + i*4 + 2] = sR[i*3+2];
                out[b*12 + i*4 + 3] = sT[i];
            }
        }
        __syncthreads();
    }
}

extern "C" void kernel_launch(void* const* d_in, const int* in_sizes, int n_in,
                              void* d_out, int out_size, void* d_ws, size_t ws_size,
                              hipStream_t stream) {
    const float* p1 = (const float*)d_in[0];
    const float* p2 = (const float*)d_in[1];
    float* out  = (float*)d_out;
    float* temp = (float*)d_ws;
    unsigned long long* nn = (unsigned long long*)((char*)d_ws + 98304);
    float* scal = (float*)((char*)d_ws + 98304 + 65536);
    const int* done = (const int*)(scal + 1);

    k_init<<<(B*N*3 + 255)/256, 256, 0, stream>>>(p1, temp, nn, scal);
    dim3 g(N/CC, N/QC, B);
    for (int it = 0; it < MAXIT; ++it) {
        k_nn<<<g, 256, 0, stream>>>(p2, temp, nn, done);
        k_step<<<1, 256, 0, stream>>>(p2, temp, nn, scal);
    }
    k_final<<<1, 256, 0, stream>>>(p1, temp, out);
}

// Round 2
// 411.620 us; speedup vs baseline: 2.3118x; 2.3118x over previous
//
#include <hip/hip_runtime.h>

#define B 4
#define N 2048
#define MAXIT 11       // body runs for it = 0..10
#define TOL 1e-4f
#define CC 512         // candidates per nn block
#define QC 256         // queries per nn block

// ---------------- workspace layout ----------------
// [0,       98304)   float temp_pc[B][N][3]
// [98304,  163840)   unsigned long long nn0[B][N]   (parity slot 0)
// [163840, 229376)   unsigned long long nn1[B][N]   (parity slot 1)
// [229376, 229380)   float prev_err
// [229380, 229428)   int done[12]

// ---------------- 3x3 helpers (double, thread-serial) ----------------
__device__ double det3(const double* M) {
    return M[0]*(M[4]*M[8]-M[5]*M[7])
         - M[1]*(M[3]*M[8]-M[5]*M[6])
         + M[2]*(M[3]*M[7]-M[4]*M[6]);
}

// SVD of 3x3 A (row-major): A = U * diag(sig) * V^T, sig sorted descending.
__device__ void svd3x3(const double* A, double* U, double* V, double* sig) {
    double S[9];
    for (int i = 0; i < 3; ++i)
        for (int j = 0; j < 3; ++j) {
            double s = 0.0;
            for (int k = 0; k < 3; ++k) s += A[k*3+i] * A[k*3+j];
            S[i*3+j] = s;
        }
    double Vm[9] = {1,0,0, 0,1,0, 0,0,1};
    for (int sweep = 0; sweep < 30; ++sweep) {
        double off = fabs(S[1]) + fabs(S[2]) + fabs(S[5]);
        double base = fabs(S[0]) + fabs(S[4]) + fabs(S[8]);
        if (off <= 1e-15 * base) break;
        for (int pi = 0; pi < 3; ++pi) {
            const int p = (pi == 2) ? 1 : 0;
            const int q = (pi == 0) ? 1 : 2;
            double apq = S[p*3+q];
            if (apq == 0.0) continue;
            double app = S[p*3+p], aqq = S[q*3+q];
            double tau = (aqq - app) / (2.0 * apq);
            double tt  = ((tau >= 0.0) ? 1.0 : -1.0) / (fabs(tau) + sqrt(1.0 + tau*tau));
            double c = 1.0 / sqrt(1.0 + tt*tt);
            double s = tt * c;
            for (int k = 0; k < 3; ++k) {
                double skp = S[k*3+p], skq = S[k*3+q];
                S[k*3+p] = c*skp - s*skq;
                S[k*3+q] = s*skp + c*skq;
            }
            for (int k = 0; k < 3; ++k) {
                double spk = S[p*3+k], sqk = S[q*3+k];
                S[p*3+k] = c*spk - s*sqk;
                S[q*3+k] = s*spk + c*sqk;
            }
            for (int k = 0; k < 3; ++k) {
                double vkp = Vm[k*3+p], vkq = Vm[k*3+q];
                Vm[k*3+p] = c*vkp - s*vkq;
                Vm[k*3+q] = s*vkp + c*vkq;
            }
        }
    }
    double lam[3] = {S[0], S[4], S[8]};
    int ord[3] = {0, 1, 2};
    for (int i = 0; i < 2; ++i)
        for (int j = i+1; j < 3; ++j)
            if (lam[ord[j]] > lam[ord[i]]) { int tmp = ord[i]; ord[i] = ord[j]; ord[j] = tmp; }
    for (int i = 0; i < 3; ++i) {
        int o = ord[i];
        double l = lam[o] > 0.0 ? lam[o] : 0.0;
        sig[i] = sqrt(l);
        for (int k = 0; k < 3; ++k) V[k*3+i] = Vm[k*3+o];
    }
    for (int i = 0; i < 3; ++i) {
        double u0 = 0, u1 = 0, u2 = 0;
        for (int k = 0; k < 3; ++k) {
            u0 += A[0*3+k] * V[k*3+i];
            u1 += A[1*3+k] * V[k*3+i];
            u2 += A[2*3+k] * V[k*3+i];
        }
        double nrm = sqrt(u0*u0 + u1*u1 + u2*u2);
        if (nrm > 1e-300) { u0 /= nrm; u1 /= nrm; u2 /= nrm; }
        else {
            double ax = U[0], ay = U[3], az = U[6];
            double bx = U[1], by = U[4], bz = U[7];
            u0 = ay*bz - az*by; u1 = az*bx - ax*bz; u2 = ax*by - ay*bx;
        }
        U[0*3+i] = u0; U[1*3+i] = u1; U[2*3+i] = u2;
    }
}

// u,s,vT = svd(H); v=vT^T; d=det(v@u^T); v[2,2]*=d; R = v' @ u^T;
// t[j] = p2c[j] - sum_k p1c[k]*R[k][j]
__device__ void compute_Rt(const double* H, const double* p1c, const double* p2c,
                           float* Rout, float* tout) {
    double U[9], V[9], sig[3];
    svd3x3(H, U, V, sig);
    double d = (det3(U) * det3(V) < 0.0) ? -1.0 : 1.0;
    V[2*3+2] *= d;
    double R[9];
    for (int i = 0; i < 3; ++i)
        for (int j = 0; j < 3; ++j) {
            double s = 0.0;
            for (int k = 0; k < 3; ++k) s += V[i*3+k] * U[j*3+k];
            R[i*3+j] = s;
        }
    for (int j = 0; j < 3; ++j) {
        double s = 0.0;
        for (int k = 0; k < 3; ++k) s += p1c[k] * R[k*3+j];
        tout[j] = (float)(p2c[j] - s);
    }
    for (int k = 0; k < 9; ++k) Rout[k] = (float)R[k];
}

__device__ inline float wred(float v) {
    v += __shfl_down(v, 32);
    v += __shfl_down(v, 16);
    v += __shfl_down(v, 8);
    v += __shfl_down(v, 4);
    v += __shfl_down(v, 2);
    v += __shfl_down(v, 1);
    return v;   // valid on lane 0 of each wave
}

// ---------------- kernels ----------------
__global__ void __launch_bounds__(256) k_init(const float* __restrict__ p1,
                                              float* __restrict__ temp,
                                              unsigned long long* __restrict__ nn0,
                                              float* scal, int* done) {
    int i = blockIdx.x * blockDim.x + threadIdx.x;
    if (i < B*N*3) temp[i] = p1[i];
    if (i < B*N)   nn0[i] = ~0ULL;
    if (i == 0)    scal[0] = 0.0f;
    if (i < 12)    done[i] = 0;
}

__global__ void __launch_bounds__(256) k_nn(const float* __restrict__ p2,
                                            const float* __restrict__ temp,
                                            unsigned long long* __restrict__ nn,
                                            const int* __restrict__ done) {
    if (*done) return;
    __shared__ float sc[CC * 3];
    const int b  = blockIdx.z;
    const int qb = blockIdx.y * QC;
    const int cb = blockIdx.x * CC;
    for (int i = threadIdx.x; i < CC*3; i += blockDim.x)
        sc[i] = temp[(b*N + cb)*3 + i];
    __syncthreads();
    const int q = qb + threadIdx.x;
    const float px = p2[(b*N+q)*3+0];
    const float py = p2[(b*N+q)*3+1];
    const float pz = p2[(b*N+q)*3+2];
    float bestd = __uint_as_float(0x7f7fffffu);  // FLT_MAX
    int   besti = 0;
    for (int j = 0; j < CC; ++j) {
        float dx = px - sc[j*3+0];
        float dy = py - sc[j*3+1];
        float dz = pz - sc[j*3+2];
        float d2 = dx*dx + dy*dy + dz*dz;
        if (d2 < bestd) { bestd = d2; besti = cb + j; }
    }
    unsigned long long pack =
        ((unsigned long long)__float_as_uint(bestd) << 32) | (unsigned int)besti;
    atomicMin(&nn[b*N + q], pack);
}

// 5 blocks: 0..3 per-batch transform, 4 = mean-err + done + reset next nn slot
__global__ void __launch_bounds__(256) k_step(const float* __restrict__ p2,
                                              float* __restrict__ temp,
                                              const unsigned long long* __restrict__ nn_cur,
                                              unsigned long long* __restrict__ nn_next,
                                              float* scal,
                                              const int* __restrict__ done_cur,
                                              int* done_next) {
    const int t   = threadIdx.x;
    const int bid = blockIdx.x;
    if (*done_cur) {
        if (bid == 4 && t == 0) *done_next = 1;
        return;
    }

    if (bid == 4) {
        // mean err over all B*N sqrt distances; reset next parity slot
        __shared__ float lds4[4];
        float s = 0.f;
        for (int i = t; i < B*N; i += 256) {
            unsigned int dbits = (unsigned int)(nn_cur[i] >> 32);
            s += sqrtf(__uint_as_float(dbits));
            nn_next[i] = ~0ULL;
        }
        s = wred(s);
        if ((t & 63) == 0) lds4[t >> 6] = s;
        __syncthreads();
        if (t == 0) {
            float tot = lds4[0] + lds4[1] + lds4[2] + lds4[3];
            float meanerr = tot / (float)(B*N);
            float prev = scal[0];
            scal[0] = meanerr;
            *done_next = (fabsf(prev - meanerr) < TOL) ? 1 : 0;
        }
        return;
    }

    const int b = bid;
    __shared__ float lred[4][9];
    __shared__ float sc1[3], sc2[3], sR[9], sT[3];
    const int wave = t >> 6, lane = t & 63;

    // phase A: centroids of temp[b] and matched (p2[b] gathered by batch-3 idx)
    float v6[6] = {0,0,0,0,0,0};
    for (int i = t; i < N; i += 256) {
        const float* tp = &temp[(b*N + i)*3];
        v6[0] += tp[0]; v6[1] += tp[1]; v6[2] += tp[2];
        const int mi = (int)(unsigned int)(nn_cur[3*N + i] & 0xffffffffULL);
        const float* mp = &p2[(b*N + mi)*3];
        v6[3] += mp[0]; v6[4] += mp[1]; v6[5] += mp[2];
    }
    #pragma unroll
    for (int k = 0; k < 6; ++k) v6[k] = wred(v6[k]);
    if (lane == 0) {
        #pragma unroll
        for (int k = 0; k < 6; ++k) lred[wave][k] = v6[k];
    }
    __syncthreads();
    if (t == 0) {
        #pragma unroll
        for (int k = 0; k < 3; ++k) {
            sc1[k] = (lred[0][k]  +lred[1][k]  +lred[2][k]  +lred[3][k])   / (float)N;
            sc2[k] = (lred[0][3+k]+lred[1][3+k]+lred[2][3+k]+lred[3][3+k]) / (float)N;
        }
    }
    __syncthreads();
    const float c1x = sc1[0], c1y = sc1[1], c1z = sc1[2];
    const float c2x = sc2[0], c2y = sc2[1], c2z = sc2[2];

    // phase B: H[j][k] = sum_n (matched - p2c)_j * (temp - p1c)_k
    float h[9];
    #pragma unroll
    for (int k = 0; k < 9; ++k) h[k] = 0.f;
    for (int i = t; i < N; i += 256) {
        const float* tp = &temp[(b*N + i)*3];
        const int mi = (int)(unsigned int)(nn_cur[3*N + i] & 0xffffffffULL);
        const float* mp = &p2[(b*N + mi)*3];
        const float bx = tp[0]-c1x, by = tp[1]-c1y, bz = tp[2]-c1z; // q1
        const float ax = mp[0]-c2x, ay = mp[1]-c2y, az = mp[2]-c2z; // q2
        h[0] += ax*bx; h[1] += ax*by; h[2] += ax*bz;
        h[3] += ay*bx; h[4] += ay*by; h[5] += ay*bz;
        h[6] += az*bx; h[7] += az*by; h[8] += az*bz;
    }
    #pragma unroll
    for (int k = 0; k < 9; ++k) h[k] = wred(h[k]);
    if (lane == 0) {
        #pragma unroll
        for (int k = 0; k < 9; ++k) lred[wave][k] = h[k];
    }
    __syncthreads();
    if (t == 0) {
        double H[9], c1d[3], c2d[3];
        for (int k = 0; k < 9; ++k)
            H[k] = (double)(lred[0][k]+lred[1][k]+lred[2][k]+lred[3][k]);
        c1d[0] = c1x; c1d[1] = c1y; c1d[2] = c1z;
        c2d[0] = c2x; c2d[1] = c2y; c2d[2] = c2z;
        compute_Rt(H, c1d, c2d, sR, sT);
    }
    __syncthreads();
    // temp[b] = temp[b] @ R + t
    for (int i = t; i < N; i += 256) {
        float* tp = &temp[(b*N + i)*3];
        const float x = tp[0], y = tp[1], z = tp[2];
        tp[0] = x*sR[0] + y*sR[3] + z*sR[6] + sT[0];
        tp[1] = x*sR[1] + y*sR[4] + z*sR[7] + sT[1];
        tp[2] = x*sR[2] + y*sR[5] + z*sR[8] + sT[2];
    }
}

// 4 blocks, one per batch
__global__ void __launch_bounds__(256) k_final(const float* __restrict__ p1,
                                               const float* __restrict__ temp,
                                               float* __restrict__ out) {
    const int b = blockIdx.x;
    const int t = threadIdx.x;
    __shared__ float lred[4][9];
    __shared__ float sc1[3], sc2[3], sR[9], sT[3];
    const int wave = t >> 6, lane = t & 63;

    float v6[6] = {0,0,0,0,0,0};
    for (int i = t; i < N; i += 256) {
        const float* pp = &p1[(b*N + i)*3];
        const float* tp = &temp[(b*N + i)*3];
        v6[0] += pp[0]; v6[1] += pp[1]; v6[2] += pp[2];
        v6[3] += tp[0]; v6[4] += tp[1]; v6[5] += tp[2];
    }
    #pragma unroll
    for (int k = 0; k < 6; ++k) v6[k] = wred(v6[k]);
    if (lane == 0) {
        #pragma unroll
        for (int k = 0; k < 6; ++k) lred[wave][k] = v6[k];
    }
    __syncthreads();
    if (t == 0) {
        #pragma unroll
        for (int k = 0; k < 3; ++k) {
            sc1[k] = (lred[0][k]  +lred[1][k]  +lred[2][k]  +lred[3][k])   / (float)N;
            sc2[k] = (lred[0][3+k]+lred[1][3+k]+lred[2][3+k]+lred[3][3+k]) / (float)N;
        }
    }
    __syncthreads();
    const float c1x = sc1[0], c1y = sc1[1], c1z = sc1[2];
    const float c2x = sc2[0], c2y = sc2[1], c2z = sc2[2];

    float h[9];
    #pragma unroll
    for (int k = 0; k < 9; ++k) h[k] = 0.f;
    for (int i = t; i < N; i += 256) {
        const float* pp = &p1[(b*N + i)*3];
        const float* tp = &temp[(b*N + i)*3];
        const float bx = pp[0]-c1x, by = pp[1]-c1y, bz = pp[2]-c1z; // q1
        const float ax = tp[0]-c2x, ay = tp[1]-c2y, az = tp[2]-c2z; // q2
        h[0] += ax*bx; h[1] += ax*by; h[2] += ax*bz;
        h[3] += ay*bx; h[4] += ay*by; h[5] += ay*bz;
        h[6] += az*bx; h[7] += az*by; h[8] += az*bz;
    }
    #pragma unroll
    for (int k = 0; k < 9; ++k) h[k] = wred(h[k]);
    if (lane == 0) {
        #pragma unroll
        for (int k = 0; k < 9; ++k) lred[wave][k] = h[k];
    }
    __syncthreads();
    if (t == 0) {
        double H[9], c1d[3], c2d[3];
        for (int k = 0; k < 9; ++k)
            H[k] = (double)(lred[0][k]+lred[1][k]+lred[2][k]+lred[3][k]);
        c1d[0] = c1x; c1d[1] = c1y; c1d[2] = c1z;
        c2d[0] = c2x; c2d[1] = c2y; c2d[2] = c2z;
        compute_Rt(H, c1d, c2d, sR, sT);
        for (int i = 0; i < 3; ++i) {
            out[b*12 + i*4 + 0] = sR[i*3+0];
            out[b*12 + i*4 + 1] = sR[i*3+1];
            out[b*12 + i*4 + 2] = sR[i*3+2];
            out[b*12 + i*4 + 3] = sT[i];
        }
    }
}

extern "C" void kernel_launch(void* const* d_in, const int* in_sizes, int n_in,
                              void* d_out, int out_size, void* d_ws, size_t ws_size,
                              hipStream_t stream) {
    const float* p1 = (const float*)d_in[0];
    const float* p2 = (const float*)d_in[1];
    float* out  = (float*)d_out;
    float* temp = (float*)d_ws;
    unsigned long long* nn0 = (unsigned long long*)((char*)d_ws + 98304);
    unsigned long long* nn1 = (unsigned long long*)((char*)d_ws + 163840);
    float* scal = (float*)((char*)d_ws + 229376);
    int*   done = (int*)((char*)d_ws + 229380);

    k_init<<<(B*N*3 + 255)/256, 256, 0, stream>>>(p1, temp, nn0, scal, done);
    dim3 g(N/CC, N/QC, B);
    for (int it = 0; it < MAXIT; ++it) {
        unsigned long long* nn_cur  = (it & 1) ? nn1 : nn0;
        unsigned long long* nn_next = (it & 1) ? nn0 : nn1;
        k_nn<<<g, 256, 0, stream>>>(p2, temp, nn_cur, &done[it]);
        k_step<<<5, 256, 0, stream>>>(p2, temp, nn_cur, nn_next, scal,
                                      &done[it], &done[it+1]);
    }
    k_final<<<4, 256, 0, stream>>>(p1, temp, out);
}